// Round 7
// baseline (287.682 us; speedup 1.0000x reference)
//
#include <hip/hip_runtime.h>
#include <hip/hip_bf16.h>

#define BB 32
#define HH 56
#define WW 56
#define CC 256
#define NPIX (BB*HH*WW)   // 100352
#define EPS 1e-5f

typedef short bf16x8 __attribute__((ext_vector_type(8)));   // 8 bf16 = 4 VGPRs
typedef float f32x4  __attribute__((ext_vector_type(4)));
typedef unsigned int u32;

// LDS x-tile: [row 0..5][col 0..29][oct 0..15][8 bf16], col stride 272 B
#define COLB 272
#define ROWB (30*COLB)    // 8160

__device__ __forceinline__ unsigned short f2bf(float f) {
    __hip_bfloat16 h = __float2bfloat16(f);
    return *reinterpret_cast<unsigned short*>(&h);
}

// ws layout: float stats[512] at byte 0 (sum[256], sumsq[256]); no y buffer --
// conv is recomputed in pass B instead of materializing a 51 MB intermediate.

// ---- shared building blocks (R6's staging, verified correct) --------------

__device__ __forceinline__ void stage_tile(const float* __restrict__ x,
    unsigned char* xs, int b, int r0, int c0, int chbase, int t)
{
    #pragma unroll
    for (int jc = 0; jc < 2; ++jc) {
        float4 a[3], c[3];
        int so[3], iv[3];
        #pragma unroll
        for (int j = 0; j < 3; ++j) {
            const int i   = (jc*3 + j)*512 + t;
            const int oct = i & 15;
            const int pix = i >> 4;
            const int row = pix / 30;
            const int col = pix - row*30;
            const int gh  = r0 - 1 + row;
            const int gw  = c0 - 1 + col;
            so[j] = row*ROWB + col*COLB + oct*16;
            iv[j] = (i < 2880);
            const bool ok = iv[j] && ((unsigned)gh < HH) && ((unsigned)gw < WW);
            const float* p = x + ((size_t)((b*HH + gh)*WW + gw))*CC + chbase + oct*8;
            a[j] = ok ? *(const float4*)p       : make_float4(0.f,0.f,0.f,0.f);
            c[j] = ok ? *(const float4*)(p + 4) : make_float4(0.f,0.f,0.f,0.f);
        }
        #pragma unroll
        for (int j = 0; j < 3; ++j) {
            if (iv[j]) {
                u32 a0 = __float_as_uint(a[j].x) + 0x8000u;
                u32 a1 = __float_as_uint(a[j].y) + 0x8000u;
                u32 a2 = __float_as_uint(a[j].z) + 0x8000u;
                u32 a3 = __float_as_uint(a[j].w) + 0x8000u;
                u32 a4 = __float_as_uint(c[j].x) + 0x8000u;
                u32 a5 = __float_as_uint(c[j].y) + 0x8000u;
                u32 a6 = __float_as_uint(c[j].z) + 0x8000u;
                u32 a7 = __float_as_uint(c[j].w) + 0x8000u;
                uint4 pk;
                pk.x = __builtin_amdgcn_perm(a1, a0, 0x07060302u);
                pk.y = __builtin_amdgcn_perm(a3, a2, 0x07060302u);
                pk.z = __builtin_amdgcn_perm(a5, a4, 0x07060302u);
                pk.w = __builtin_amdgcn_perm(a7, a6, 0x07060302u);
                *(uint4*)(xs + so[j]) = pk;
            }
        }
    }
}

// A-operand = weights (m = lane&15 = local out-ch, k-octet = quad).
__device__ __forceinline__ void gather_w(const float* __restrict__ wgt,
    int chbase, int w, int lane, bf16x8* wfrag)
{
    const int m = lane & 15;
    const int q = lane >> 4;
    #pragma unroll
    for (int s = 0; s < 5; ++s) {
        const int o  = s*4 + q;
        const int g  = (o >= 10);
        const int tp = o - g*10;
        const int tp0 = (tp == 9) ? 0 : tp;
        const bool val = (tp < 9) && ((m >> 3) == g);
        const float* wp = wgt + tp0*8*CC + chbase + w*16 + m;
        #pragma unroll
        for (int ci = 0; ci < 8; ++ci) {
            float f = val ? wp[ci*CC] : 0.f;
            wfrag[s][ci] = (short)f2bf(f);
        }
    }
}

// B-operand = pixels (n = lane&15 = pixel in 4x4 tile, k-octet = quad).
__device__ __forceinline__ void calc_aoff(int lane, int w, int* aoff)
{
    const int q  = lane >> 4;
    const int pr = (lane & 15) >> 2;
    const int pc = lane & 3;
    #pragma unroll
    for (int s = 0; s < 5; ++s) {
        const int o = s*4 + q;
        const int g = (o >= 10);
        int tp = o - g*10;
        if (tp == 9) tp = 0;
        const int dh = tp / 3, dw = tp - dh*3;
        aoff[s] = (pr + dh)*ROWB + (pc + dw)*COLB + (2*w + g)*16;
    }
}

// ---- pass A: conv -> per-channel sum/sumsq only. ZERO stores to HBM. ------
__global__ __launch_bounds__(512) void k1a_stats(
    const float* __restrict__ x, const float* __restrict__ wgt,
    float* __restrict__ stats)
{
    __shared__ __align__(16) unsigned char xs[6*ROWB];
    __shared__ __align__(16) float bsum[128], bsq[128];

    const int cq   = blockIdx.x & 1;
    const int chh  = blockIdx.x >> 1;
    const int hb   = blockIdx.y;
    const int b    = blockIdx.z;
    const int t    = threadIdx.x;
    const int lane = t & 63;
    const int w    = t >> 6;
    const int r0   = hb*4, c0 = cq*28;
    const int chbase = chh*128;

    stage_tile(x, xs, b, r0, c0, chbase, t);

    bf16x8 wfrag[5];
    gather_w(wgt, chbase, w, lane, wfrag);
    int aoff[5];
    calc_aoff(lane, w, aoff);

    __syncthreads();

    f32x4 s1 = {0.f,0.f,0.f,0.f}, s2 = {0.f,0.f,0.f,0.f};
    #pragma unroll
    for (int ct = 0; ct < 7; ++ct) {
        f32x4 acc = {0.f,0.f,0.f,0.f};
        #pragma unroll
        for (int s = 0; s < 5; ++s) {
            bf16x8 xf = *(const bf16x8*)(xs + aoff[s] + ct*(4*COLB));
            acc = __builtin_amdgcn_mfma_f32_16x16x32_bf16(wfrag[s], xf, acc, 0, 0, 0);
        }
        #pragma unroll
        for (int i = 0; i < 4; ++i) { s1[i] += acc[i]; s2[i] += acc[i]*acc[i]; }
    }

    // lanes with same (w,q) hold the same 4 channels, different pixels:
    // butterfly over the 16-lane group, then one writer per (w,q).
    #pragma unroll
    for (int d = 1; d < 16; d <<= 1) {
        #pragma unroll
        for (int i = 0; i < 4; ++i) {
            s1[i] += __shfl_xor(s1[i], d);
            s2[i] += __shfl_xor(s2[i], d);
        }
    }
    const int q = lane >> 4;
    if ((lane & 15) == 0) {
        *(f32x4*)&bsum[w*16 + q*4] = s1;   // unique writer per slot
        *(f32x4*)&bsq[w*16 + q*4]  = s2;
    }
    __syncthreads();
    if (t < 128) {
        atomicAdd(&stats[chbase + t],       bsum[t]);
        atomicAdd(&stats[256 + chbase + t], bsq[t]);
    }
}

// ---- pass B: recompute conv, fused BN+ReLU, coalesced fp32 NT store. ------
// C layout (swapped operands): col = lane&15 = pixel, row = q*4+i = channel
// -> each lane stores ONE contiguous float4; a wave store inst covers 16
// fully-written 64-B lines.
__global__ __launch_bounds__(512) void k1b_out(
    const float* __restrict__ x, const float* __restrict__ wgt,
    const float* __restrict__ stats, const float* __restrict__ gamma,
    const float* __restrict__ beta, float* __restrict__ out)
{
    __shared__ __align__(16) unsigned char xs[6*ROWB];

    const int cq   = blockIdx.x & 1;
    const int chh  = blockIdx.x >> 1;
    const int hb   = blockIdx.y;
    const int b    = blockIdx.z;
    const int t    = threadIdx.x;
    const int lane = t & 63;
    const int w    = t >> 6;
    const int r0   = hb*4, c0 = cq*28;
    const int chbase = chh*128;

    stage_tile(x, xs, b, r0, c0, chbase, t);

    bf16x8 wfrag[5];
    gather_w(wgt, chbase, w, lane, wfrag);
    int aoff[5];
    calc_aoff(lane, w, aoff);

    // per-lane scale/shift for its 4 channels (L2-hot 2 KB; conv bias
    // cancels exactly under BN mean-subtraction)
    const int q  = lane >> 4;
    const int c4 = chbase + w*16 + q*4;
    f32x4 sum = *(const f32x4*)(stats + c4);
    f32x4 ssq = *(const f32x4*)(stats + 256 + c4);
    f32x4 gm  = *(const f32x4*)(gamma + c4);
    f32x4 bt  = *(const f32x4*)(beta + c4);
    f32x4 sc, sh;
    const float inv_n = 1.f / (float)NPIX;
    #pragma unroll
    for (int i = 0; i < 4; ++i) {
        float mean = sum[i] * inv_n;
        float var  = ssq[i] * inv_n - mean*mean;
        sc[i] = gm[i] * rsqrtf(var + EPS);
        sh[i] = bt[i] - mean * sc[i];
    }

    __syncthreads();

    const int p  = lane & 15;            // pixel index in 4x4 tile
    const int h  = r0 + (p >> 2);
    const int wc0 = c0 + (p & 3);
    #pragma unroll
    for (int ct = 0; ct < 7; ++ct) {
        f32x4 acc = {0.f,0.f,0.f,0.f};
        #pragma unroll
        for (int s = 0; s < 5; ++s) {
            bf16x8 xf = *(const bf16x8*)(xs + aoff[s] + ct*(4*COLB));
            acc = __builtin_amdgcn_mfma_f32_16x16x32_bf16(wfrag[s], xf, acc, 0, 0, 0);
        }
        f32x4 o;
        #pragma unroll
        for (int i = 0; i < 4; ++i)
            o[i] = fmaxf(0.f, acc[i]*sc[i] + sh[i]);
        f32x4* op = (f32x4*)(out + ((size_t)((b*HH + h)*WW + wc0 + ct*4))*CC + c4);
        __builtin_nontemporal_store(o, op);
    }
}

extern "C" void kernel_launch(void* const* d_in, const int* in_sizes, int n_in,
                              void* d_out, int out_size, void* d_ws, size_t ws_size,
                              hipStream_t stream) {
    const float* x     = (const float*)d_in[0];
    const float* wgt   = (const float*)d_in[1];
    // d_in[2] = conv bias: cancels exactly under BN mean-subtraction -- unused
    const float* gamma = (const float*)d_in[3];
    const float* beta  = (const float*)d_in[4];
    float* out = (float*)d_out;

    float* stats = (float*)d_ws;   // 512 floats

    hipMemsetAsync(stats, 0, 2048, stream);
    k1a_stats<<<dim3(4, 14, BB), 512, 0, stream>>>(x, wgt, stats);
    k1b_out<<<dim3(4, 14, BB), 512, 0, stream>>>(x, wgt, stats, gamma, beta, out);
}